// Round 13
// baseline (675.221 us; speedup 1.0000x reference)
//
#include <hip/hip_runtime.h>
#include <hip/hip_bf16.h>
#include <math.h>

#define D 128
#define ED 16
#define NUM_GRAPHS 64
#define SCAN_CHUNK 2048

// ---------------- CSR build ----------------

__global__ __launch_bounds__(256) void scan_reduce_kernel(const int* __restrict__ deg,
                                                          int* __restrict__ bsum, int N) {
  int b = blockIdx.x, tid = threadIdx.x;
  int base = b * SCAN_CHUNK + tid * 8;
  int s = 0;
#pragma unroll
  for (int j = 0; j < 8; ++j) {
    int idx = base + j;
    if (idx < N) s += deg[idx];
  }
#pragma unroll
  for (int off = 1; off < 64; off <<= 1) s += __shfl_xor(s, off);
  __shared__ int ws[4];
  int lane = tid & 63, w = tid >> 6;
  if (lane == 0) ws[w] = s;
  __syncthreads();
  if (tid == 0) bsum[b] = ws[0] + ws[1] + ws[2] + ws[3];
}

// one wave: block-sum scan + per-graph inverse counts (batch sorted)
__global__ void scan_bsum_kernel(const int* __restrict__ bsum, int* __restrict__ boff,
                                 int* __restrict__ rowptrN, int B,
                                 const int* __restrict__ batch, float* __restrict__ ginv,
                                 int N) {
  int tid = threadIdx.x;  // 64 lanes
  int v = (tid < B) ? bsum[tid] : 0;
  int x = v;
#pragma unroll
  for (int off = 1; off < 64; off <<= 1) {
    int y = __shfl_up(x, off);
    if (tid >= off) x += y;
  }
  if (tid < B) boff[tid] = x - v;
  if (tid == 63) *rowptrN = x;

  // graph start boundaries: lower_bound(batch, tid)
  int lo = 0, hi = N;
  while (lo < hi) {
    int mid = (lo + hi) >> 1;
    if (batch[mid] < tid) lo = mid + 1;
    else hi = mid;
  }
  int startg = lo;
  int nxt = __shfl_down(startg, 1);
  if (tid == 63) nxt = N;
  if (tid < NUM_GRAPHS) ginv[tid] = 1.0f / fmaxf((float)(nxt - startg), 1.0f);
}

// writes rowptr AND cursor copy (for scatter's atomic slot allocation)
__global__ __launch_bounds__(256) void scan_write_kernel(const int* __restrict__ deg,
                                                         const int* __restrict__ boff,
                                                         int* __restrict__ rowptr,
                                                         int* __restrict__ cursor, int N) {
  int b = blockIdx.x, tid = threadIdx.x;
  int lane = tid & 63, w = tid >> 6;
  int base = b * SCAN_CHUNK + tid * 8;
  int v[8];
  int s = 0;
#pragma unroll
  for (int j = 0; j < 8; ++j) {
    int idx = base + j;
    v[j] = (idx < N) ? deg[idx] : 0;
    s += v[j];
  }
  int t = s, x = t;
#pragma unroll
  for (int off = 1; off < 64; off <<= 1) {
    int y = __shfl_up(x, off);
    if (lane >= off) x += y;
  }
  __shared__ int wsum[4];
  if (lane == 63) wsum[w] = x;
  __syncthreads();
  int wexc = 0;
  for (int i = 0; i < w; ++i) wexc += wsum[i];
  int run = boff[b] + wexc + (x - t);
#pragma unroll
  for (int j = 0; j < 8; ++j) {
    int idx = base + j;
    if (idx < N) {
      rowptr[idx] = run;
      cursor[idx] = run;
    }
    run += v[j];
  }
}

__global__ void scatter_kernel(const int* __restrict__ src, const int* __restrict__ dst,
                               int* __restrict__ cursor, int2* __restrict__ csr, int E) {
  int e = blockIdx.x * 256 + threadIdx.x;
  if (e >= E) return;
  int d = dst[e];
  int pos = atomicAdd(&cursor[d], 1);
  csr[pos] = make_int2(src[e], e);
}

// ---------------- dense xl = x@Wl, xr = x@Wr (+ optional fused deg blocks) ------

__global__ __launch_bounds__(256) void gemm2_deg_kernel(const float* __restrict__ x,
                                                        const float* __restrict__ Wl,
                                                        const float* __restrict__ Wr,
                                                        float* __restrict__ xl,
                                                        float* __restrict__ xr, int N,
                                                        const int* __restrict__ dstp,
                                                        int* __restrict__ deg, int E,
                                                        int gB) {
  __shared__ float xst[D][64];
  __shared__ float ws[16][256];
  int tid = threadIdx.x;

  if (blockIdx.x >= gB) {  // degree-histogram blocks (layer-1 only)
    int e = (blockIdx.x - gB) * 256 + tid;
    if (e < E) atomicAdd(&deg[dstp[e]], 1);
    return;
  }

  int base = blockIdx.x * 64;

#pragma unroll
  for (int j = 0; j < 8; ++j) {
    int idx = tid + j * 256;
    int row = idx & 63;
    int c4 = idx >> 6;
    int n = base + row;
    float4 v = make_float4(0.f, 0.f, 0.f, 0.f);
    if (n < N) v = *(const float4*)&x[(size_t)n * D + c4 * 4];
    xst[c4 * 4 + 0][row] = v.x;
    xst[c4 * 4 + 1][row] = v.y;
    xst[c4 * 4 + 2][row] = v.z;
    xst[c4 * 4 + 3][row] = v.w;
  }

  int tn = tid & 15;
  int tc = tid >> 4;
  float acc[4][16];
#pragma unroll
  for (int i = 0; i < 4; ++i)
#pragma unroll
    for (int j = 0; j < 16; ++j) acc[i][j] = 0.f;

  for (int kb = 0; kb < D; kb += 16) {
    __syncthreads();
#pragma unroll
    for (int j = 0; j < 4; ++j) {
      int idx = tid + j * 256;
      int c4 = idx & 63;
      int kk = idx >> 6;
      int c = c4 * 4;
      const float* Wp = (c < D) ? &Wl[(size_t)(kb + kk) * D + c]
                                : &Wr[(size_t)(kb + kk) * D + (c - D)];
      *(float4*)&ws[kk][c] = *(const float4*)Wp;
    }
    __syncthreads();
#pragma unroll
    for (int kk = 0; kk < 16; ++kk) {
      float4 xv = *(float4*)&xst[kb + kk][tn * 4];
      float xa[4] = {xv.x, xv.y, xv.z, xv.w};
      float4 w0 = *(float4*)&ws[kk][tc * 16 + 0];
      float4 w1 = *(float4*)&ws[kk][tc * 16 + 4];
      float4 w2 = *(float4*)&ws[kk][tc * 16 + 8];
      float4 w3 = *(float4*)&ws[kk][tc * 16 + 12];
      float wa[16] = {w0.x, w0.y, w0.z, w0.w, w1.x, w1.y, w1.z, w1.w,
                      w2.x, w2.y, w2.z, w2.w, w3.x, w3.y, w3.z, w3.w};
#pragma unroll
      for (int i = 0; i < 4; ++i)
#pragma unroll
        for (int j = 0; j < 16; ++j) acc[i][j] = fmaf(xa[i], wa[j], acc[i][j]);
    }
  }

#pragma unroll
  for (int i = 0; i < 4; ++i) {
    int n = base + tn * 4 + i;
    if (n >= N) continue;
    float* outp;
    int c;
    if (tc < 8) { outp = xl; c = tc * 16; }
    else        { outp = xr; c = (tc - 8) * 16; }
#pragma unroll
    for (int j4 = 0; j4 < 4; ++j4) {
      float4 v = make_float4(acc[i][j4 * 4 + 0], acc[i][j4 * 4 + 1],
                             acc[i][j4 * 4 + 2], acc[i][j4 * 4 + 3]);
      *(float4*)&outp[(size_t)n * D + c + j4 * 4] = v;
    }
  }
}

// ---------------- fused GATv2: persistent waves, self-loop fused, no max --------
// FINAL=false: write y rows. FINAL=true: ReLU'd row scaled by 1/cnt and
// atomically accumulated into the pooled output (fuses relu+mean-pool).

template <bool FINAL>
__global__ __launch_bounds__(256) void gat_fused_kernel(
    const float* __restrict__ xl, const float* __restrict__ xr,
    const int* __restrict__ rowptr, const int2* __restrict__ csr,
    const float* __restrict__ ea, const float* __restrict__ We,
    const float* __restrict__ att, const float* __restrict__ bias,
    float* __restrict__ y, const int* __restrict__ batch,
    const float* __restrict__ ginv, float* __restrict__ out, int N, int nwaves) {
  __shared__ float ea_lds[4][4][16];
  int lane = threadIdx.x & 63;
  int wid = threadIdx.x >> 6;
  int gwave = blockIdx.x * 4 + wid;

  float weL[ED], weH[ED];
#pragma unroll
  for (int k = 0; k < ED; ++k) {
    float2 w = *(const float2*)&We[k * D + 2 * lane];
    weL[k] = w.x;
    weH[k] = w.y;
  }
  float2 attv = *(const float2*)&att[2 * lane];
  float2 bv = *(const float2*)&bias[2 * lane];

  int ej = lane >> 4;
  int ek = lane & 15;

  for (int n = gwave; n < N; n += nwaves) {
    float2 xrv = *(const float2*)&xr[(size_t)n * D + 2 * lane];
    float2 xsl = *(const float2*)&xl[(size_t)n * D + 2 * lane];
    int beg = rowptr[n], end = rowptr[n + 1];

    float denom = 0.f, acc0 = 0.f, acc1 = 0.f, easum = 0.f;

    for (int i = beg; i < end; i += 4) {
      int cnt = end - i;
      int last = end - 1;
      int i1 = (i + 1 < end) ? i + 1 : last;
      int i2 = (i + 2 < end) ? i + 2 : last;
      int i3 = (i + 3 < end) ? i + 3 : last;
      int2 c0 = csr[i], c1 = csr[i1], c2 = csr[i2], c3 = csr[i3];

      float2 xs0 = *(const float2*)&xl[(size_t)c0.x * D + 2 * lane];
      float2 xs1 = *(const float2*)&xl[(size_t)c1.x * D + 2 * lane];
      float2 xs2 = *(const float2*)&xl[(size_t)c2.x * D + 2 * lane];
      float2 xs3 = *(const float2*)&xl[(size_t)c3.x * D + 2 * lane];

      int eidj = (ej == 0) ? c0.y : (ej == 1) ? c1.y : (ej == 2) ? c2.y : c3.y;
      float a = ea[(size_t)eidj * ED + ek];
      ea_lds[wid][ej][ek] = a;
      easum += (ej < cnt) ? a : 0.f;

      float pre[4];
      float2 xsa[4] = {xs0, xs1, xs2, xs3};
#pragma unroll
      for (int j = 0; j < 4; ++j) {
        const float4* eap = (const float4*)&ea_lds[wid][j][0];
        float4 q0 = eap[0], q1 = eap[1], q2 = eap[2], q3 = eap[3];
        float av[16] = {q0.x, q0.y, q0.z, q0.w, q1.x, q1.y, q1.z, q1.w,
                        q2.x, q2.y, q2.z, q2.w, q3.x, q3.y, q3.z, q3.w};
        float e0 = 0.f, e1 = 0.f;
#pragma unroll
        for (int k = 0; k < ED; ++k) {
          e0 = fmaf(av[k], weL[k], e0);
          e1 = fmaf(av[k], weH[k], e1);
        }
        float t0 = xsa[j].x + xrv.x + e0;
        t0 = (t0 > 0.f) ? t0 : 0.2f * t0;
        float t1 = xsa[j].y + xrv.y + e1;
        t1 = (t1 > 0.f) ? t1 : 0.2f * t1;
        pre[j] = fmaf(t0, attv.x, t1 * attv.y);
      }

#pragma unroll
      for (int off = 32; off > 0; off >>= 1) {
#pragma unroll
        for (int j = 0; j < 4; ++j) pre[j] += __shfl_xor(pre[j], off);
      }

#pragma unroll
      for (int j = 0; j < 4; ++j) {
        float w = (j < cnt) ? __expf(pre[j]) : 0.f;
        denom += w;
        acc0 = fmaf(w, xsa[j].x, acc0);
        acc1 = fmaf(w, xsa[j].y, acc1);
      }
    }

    // self-loop last: ea mean from in-register sums
    easum += __shfl_xor(easum, 16);
    easum += __shfl_xor(easum, 32);
    float dg = fmaxf((float)(end - beg), 1.0f);
    if (ej == 0) ea_lds[wid][0][ek] = easum / dg;
    {
      const float4* eap = (const float4*)&ea_lds[wid][0][0];
      float4 q0 = eap[0], q1 = eap[1], q2 = eap[2], q3 = eap[3];
      float av[16] = {q0.x, q0.y, q0.z, q0.w, q1.x, q1.y, q1.z, q1.w,
                      q2.x, q2.y, q2.z, q2.w, q3.x, q3.y, q3.z, q3.w};
      float e0 = 0.f, e1 = 0.f;
#pragma unroll
      for (int k = 0; k < ED; ++k) {
        e0 = fmaf(av[k], weL[k], e0);
        e1 = fmaf(av[k], weH[k], e1);
      }
      float t0 = xsl.x + xrv.x + e0;
      t0 = (t0 > 0.f) ? t0 : 0.2f * t0;
      float t1 = xsl.y + xrv.y + e1;
      t1 = (t1 > 0.f) ? t1 : 0.2f * t1;
      float p = fmaf(t0, attv.x, t1 * attv.y);
#pragma unroll
      for (int off = 32; off > 0; off >>= 1) p += __shfl_xor(p, off);
      float w = __expf(p);
      denom += w;
      acc0 = fmaf(w, xsl.x, acc0);
      acc1 = fmaf(w, xsl.y, acc1);
    }

    float inv = 1.0f / (denom + 1e-16f);
    float o0 = fmaxf(fmaf(acc0, inv, bv.x), 0.f);
    float o1 = fmaxf(fmaf(acc1, inv, bv.y), 0.f);
    if (FINAL) {
      int g = batch[n];
      float sc = ginv[g];
      atomicAdd(&out[(size_t)g * D + 2 * lane], o0 * sc);
      atomicAdd(&out[(size_t)g * D + 2 * lane + 1], o1 * sc);
    } else {
      *(float2*)&y[(size_t)n * D + 2 * lane] = make_float2(o0, o1);
    }
  }
}

// ---------------- launch ----------------

static inline size_t alignup(size_t v) { return (v + 255) & ~(size_t)255; }

extern "C" void kernel_launch(void* const* d_in, const int* in_sizes, int n_in,
                              void* d_out, int out_size, void* d_ws, size_t ws_size,
                              hipStream_t stream) {
  const float* xnode = (const float*)d_in[0];
  const int* eidx = (const int*)d_in[1];
  const int* batch = (const int*)d_in[2];
  const float* eattr = (const float*)d_in[3];
  const float* Wl1 = (const float*)d_in[4];
  const float* Wr1 = (const float*)d_in[5];
  const float* We1 = (const float*)d_in[6];
  const float* att1 = (const float*)d_in[7];
  const float* b1 = (const float*)d_in[8];
  const float* Wl2 = (const float*)d_in[9];
  const float* Wr2 = (const float*)d_in[10];
  const float* We2 = (const float*)d_in[11];
  const float* att2 = (const float*)d_in[12];
  const float* b2 = (const float*)d_in[13];
  float* out = (float*)d_out;

  int N = in_sizes[0] / D;
  int E = in_sizes[3] / ED;
  const int* srcp = eidx;
  const int* dstp = eidx + E;
  int B = (N + SCAN_CHUNK - 1) / SCAN_CHUNK;

  char* p = (char*)d_ws;
  int* rowptr = (int*)p;    p += alignup((size_t)(N + 1) * 4);
  int* deg = (int*)p;       p += alignup((size_t)N * 4);
  int* cursor = (int*)p;    p += alignup((size_t)N * 4);
  int* bsum = (int*)p;      p += alignup((size_t)B * 4);
  int* boff = (int*)p;      p += alignup((size_t)B * 4);
  float* ginv = (float*)p;  p += alignup((size_t)NUM_GRAPHS * 4);
  int2* csr = (int2*)p;     p += alignup((size_t)E * 8);
  float* xlb = (float*)p;   p += alignup((size_t)N * D * 4);
  float* xrb = (float*)p;   p += alignup((size_t)N * D * 4);
  float* yb = (float*)p;    p += alignup((size_t)N * D * 4);

  hipMemsetAsync(deg, 0, (size_t)N * 4, stream);
  hipMemsetAsync(out, 0, (size_t)NUM_GRAPHS * D * 4, stream);

  int gB = (N + 63) / 64;          // gemm blocks
  int degB = (E + 255) / 256;      // deg blocks
  int gblocks = 2048;              // persistent gat grid
  int nwaves = gblocks * 4;

  // layer 1 gemm + deg histogram fused (independent work)
  gemm2_deg_kernel<<<gB + degB, 256, 0, stream>>>(xnode, Wl1, Wr1, xlb, xrb, N,
                                                  dstp, deg, E, gB);
  scan_reduce_kernel<<<B, 256, 0, stream>>>(deg, bsum, N);
  scan_bsum_kernel<<<1, 64, 0, stream>>>(bsum, boff, rowptr + N, B, batch, ginv, N);
  scan_write_kernel<<<B, 256, 0, stream>>>(deg, boff, rowptr, cursor, N);
  scatter_kernel<<<degB, 256, 0, stream>>>(srcp, dstp, cursor, csr, E);

  // layer 1 gat
  gat_fused_kernel<false><<<gblocks, 256, 0, stream>>>(
      xlb, xrb, rowptr, csr, eattr, We1, att1, b1, yb, nullptr, nullptr, nullptr,
      N, nwaves);
  // layer 2 gemm (no deg blocks)
  gemm2_deg_kernel<<<gB, 256, 0, stream>>>(yb, Wl2, Wr2, xlb, xrb, N,
                                           nullptr, nullptr, 0, gB);
  // layer 2 gat -> fused relu+mean-pool into out
  gat_fused_kernel<true><<<gblocks, 256, 0, stream>>>(
      xlb, xrb, rowptr, csr, eattr, We2, att2, b2, nullptr, batch, ginv, out,
      N, nwaves);

  (void)ws_size; (void)n_in; (void)out_size;
}